// Round 3
// baseline (607.581 us; speedup 1.0000x reference)
//
#include <hip/hip_runtime.h>

#define LQ 300
#define NB 32
#define SK 1024
#define EE 256
#define HH 8
#define DH 32
#define BH 256   // N*H
#define LPAD 304
#define NLT 19   // ceil(300/16)

typedef short short8 __attribute__((ext_vector_type(8)));
typedef short short4v __attribute__((ext_vector_type(4)));
typedef float f32x4 __attribute__((ext_vector_type(4)));

#define MFMA16(a, b, c) __builtin_amdgcn_mfma_f32_16x16x32_bf16((a), (b), (c), 0, 0, 0)

__device__ __forceinline__ short f2bf(float f) {
    unsigned u = __float_as_uint(f);
    u += 0x7FFFu + ((u >> 16) & 1u);   // round-to-nearest-even
    return (short)(u >> 16);
}

__device__ __forceinline__ short8 cvt8(const float* __restrict__ p) {
    float4 x = *(const float4*)p;
    float4 y = *(const float4*)(p + 4);
    short8 r;
    r[0] = f2bf(x.x); r[1] = f2bf(x.y); r[2] = f2bf(x.z); r[3] = f2bf(x.w);
    r[4] = f2bf(y.x); r[5] = f2bf(y.y); r[6] = f2bf(y.z); r[7] = f2bf(y.w);
    return r;
}

// ---------------------------------------------------------------------------
// prep: convert in_proj_weight (3E x E) + out_proj_weight (E x E) to bf16
// ---------------------------------------------------------------------------
__global__ __launch_bounds__(256) void prep_kernel(
    const float* __restrict__ ipw, const float* __restrict__ opw,
    short* __restrict__ wbf)
{
    int i = blockIdx.x * 256 + threadIdx.x;   // 0..65535
    int base = i * 4;
    const float* src = (base < 3 * EE * EE) ? (ipw + base) : (opw + base - 3 * EE * EE);
    float4 x = *(const float4*)src;
    short4v r;
    r[0] = f2bf(x.x); r[1] = f2bf(x.y); r[2] = f2bf(x.z); r[3] = f2bf(x.w);
    *(short4v*)(wbf + base) = r;
}

// ---------------------------------------------------------------------------
// QKV projection: wave = 16 tokens x ALL 256 features, K=256. X read once.
// Epilogue staged through LDS -> coalesced 16B stores.
// ---------------------------------------------------------------------------
__global__ __launch_bounds__(256) void proj_kernel(
    const float* __restrict__ query, const float* __restrict__ key,
    const float* __restrict__ value, const short* __restrict__ wbf,
    const float* __restrict__ bias,
    short* __restrict__ qws, short* __restrict__ kws, short* __restrict__ vws)
{
    __shared__ __align__(16) short stage[4][16 * 264];
    int wv = threadIdx.x >> 6;
    int wave = blockIdx.x * 4 + wv;
    int lid = threadIdx.x & 63, quad = lid >> 4, l16 = lid & 15;

    int u = wave, p;
    const float* X;
    if (u < 600)             { p = 0; X = query; }
    else if (u < 600 + 2048) { p = 1; X = key;   u -= 600; }
    else                     { p = 2; X = value; u -= 2648; }
    int t = u * 16 + l16;
    int tokbase = u * 16;

    const short* wb = wbf + p * EE * EE;
    f32x4 acc[16];
    #pragma unroll
    for (int f = 0; f < 16; f++) acc[f] = (f32x4){0.f, 0.f, 0.f, 0.f};

    for (int ks = 0; ks < 8; ks++) {
        short8 af = cvt8(X + (size_t)t * EE + ks * 32 + quad * 8);
        #pragma unroll
        for (int f = 0; f < 16; f++) {
            short8 bf = *(const short8*)(wb + (size_t)(f * 16 + l16) * EE + ks * 32 + quad * 8);
            acc[f] = MFMA16(af, bf, acc[f]);
        }
    }

    // stage 16x256 bf16 tile in LDS (per-wave region, wave-synchronous)
    short* st = stage[wv];
    #pragma unroll
    for (int f = 0; f < 16; f++) {
        int feat = f * 16 + l16;
        float bia = bias[p * EE + feat];
        #pragma unroll
        for (int r = 0; r < 4; r++) {
            float v = acc[f][r] + bia;
            if (p == 0) v *= 0.17677669529663687f;   // Dh^-0.5
            st[(quad * 4 + r) * 264 + feat] = f2bf(v);
        }
    }

    // coalesced 16B stores: 512 chunks of 8 shorts
    #pragma unroll
    for (int k = 0; k < 8; k++) {
        int chunk = k * 64 + lid;
        int tok = chunk >> 5, hh = (chunk >> 2) & 7, q4 = chunk & 3;
        short8 x = *(const short8*)(st + tok * 264 + hh * 32 + q4 * 8);
        int gt = tokbase + tok;
        int nn = gt & 31, s = gt >> 5;
        int bb = nn * 8 + hh;
        if (p == 0)
            *(short8*)(qws + ((size_t)bb * LPAD + s) * DH + q4 * 8) = x;
        else if (p == 1)
            *(short8*)(kws + ((size_t)bb * SK + s) * DH + q4 * 8) = x;
        else
            *(short8*)(vws + ((size_t)bb * SK + s) * DH + q4 * 8) = x;
    }
}

// ---------------------------------------------------------------------------
// V transpose: vt[b][d][s] from vws[b][s][d], LDS tiled, coalesced both sides
// ---------------------------------------------------------------------------
__global__ __launch_bounds__(256) void vtrans_kernel(
    const short* __restrict__ vws, short* __restrict__ vt)
{
    __shared__ __align__(16) short tile[32][272];
    int b = blockIdx.x >> 2, s0 = (blockIdx.x & 3) * 256;
    const short* src = vws + ((size_t)b * SK + s0) * DH;
    #pragma unroll
    for (int pass = 0; pass < 4; pass++) {
        int i = pass * 256 + threadIdx.x;
        int sl = i >> 2, d0 = (i & 3) * 8;
        short8 x = *(const short8*)(src + sl * DH + d0);
        #pragma unroll
        for (int j = 0; j < 8; j++) tile[d0 + j][sl] = x[j];
    }
    __syncthreads();
    short* dst = vt + (size_t)b * DH * SK + s0;
    #pragma unroll
    for (int pass = 0; pass < 4; pass++) {
        int i = pass * 256 + threadIdx.x;
        int d = i >> 5, sl0 = (i & 31) * 8;
        *(short8*)(dst + (size_t)d * SK + sl0) = *(const short8*)(&tile[d][sl0]);
    }
}

// ---------------------------------------------------------------------------
// Flash attention WITHOUT max-subtraction (scores bounded; exp cannot
// overflow fp32). No shuffles / no rescale in the loop; partials add.
// Block = (b, 16-row L-tile); 4 waves split S (256 each).
// ---------------------------------------------------------------------------
__global__ __launch_bounds__(256) void attn_kernel(
    const short* __restrict__ qws, const short* __restrict__ kws,
    const short* __restrict__ vt, const float* __restrict__ gauss,
    const unsigned char* __restrict__ mask, short* __restrict__ ows)
{
    __shared__ __align__(16) short pbuf[4][16 * 80];
    __shared__ float obuf[4][16][32];
    __shared__ float lbuf[4][16];

    int b = blockIdx.x / NLT, lt = blockIdx.x % NLT;
    int wv = threadIdx.x >> 6;
    int lid = threadIdx.x & 63, quad = lid >> 4, l16 = lid & 15;
    int n = b >> 3, h = b & 7;

    int ql = lt * 16 + l16;
    short8 qa = *(const short8*)(qws + ((size_t)b * LPAD + ql) * DH + quad * 8);

    f32x4 o0 = {0.f, 0.f, 0.f, 0.f}, o1 = {0.f, 0.f, 0.f, 0.f};
    float ls[4] = {0.f, 0.f, 0.f, 0.f};

    const float* gbase = gauss + (size_t)b * LQ * SK;
    const float* grow[4];
    #pragma unroll
    for (int r = 0; r < 4; r++) {
        int l = lt * 16 + quad * 4 + r;
        grow[r] = gbase + (size_t)(l < LQ ? l : LQ - 1) * SK + l16;
    }

    short* pb = pbuf[wv];
    int sw = quad << 4;               // store-side XOR swizzle
    int rw = (l16 >> 2) << 4;         // read-side key
    int sbase = wv * 256;

    for (int it = 0; it < 4; it++) {
        int sc = sbase + it * 64;

        short8 kb[4];
        #pragma unroll
        for (int c = 0; c < 4; c++)
            kb[c] = *(const short8*)(kws + ((size_t)b * SK + sc + c * 16 + l16) * DH + quad * 8);

        short8 vb[2][2];
        #pragma unroll
        for (int t2 = 0; t2 < 2; t2++)
            #pragma unroll
            for (int k2 = 0; k2 < 2; k2++)
                vb[t2][k2] = *(const short8*)(vt + ((size_t)b * DH + t2 * 16 + l16) * SK + sc + k2 * 32 + quad * 8);

        bool mk[4];
        #pragma unroll
        for (int c = 0; c < 4; c++) mk[c] = mask[n * SK + sc + c * 16 + l16] != 0;

        float g[4][4];
        #pragma unroll
        for (int r = 0; r < 4; r++)
            #pragma unroll
            for (int c = 0; c < 4; c++) g[r][c] = grow[r][sc + c * 16];

        f32x4 z = {0.f, 0.f, 0.f, 0.f};
        f32x4 cc[4];
        #pragma unroll
        for (int c = 0; c < 4; c++) cc[c] = MFMA16(qa, kb[c], z);

        #pragma unroll
        for (int r = 0; r < 4; r++) {
            int row = quad * 4 + r;
            #pragma unroll
            for (int c = 0; c < 4; c++) {
                float p = __expf(cc[c][r] + g[r][c]);
                p = mk[c] ? 0.f : p;
                ls[r] += p;
                pb[row * 80 + ((c * 16 + l16) ^ sw)] = f2bf(p);
            }
        }

        short8 pa0 = *(const short8*)(pb + l16 * 80 + ((0 + quad * 8) ^ rw));
        short8 pa1 = *(const short8*)(pb + l16 * 80 + ((32 + quad * 8) ^ rw));

        o0 = MFMA16(pa0, vb[0][0], o0);
        o0 = MFMA16(pa1, vb[0][1], o0);
        o1 = MFMA16(pa0, vb[1][0], o1);
        o1 = MFMA16(pa1, vb[1][1], o1);
    }

    // single end-of-loop row-sum reduction (16 lanes per quad)
    #pragma unroll
    for (int r = 0; r < 4; r++) {
        #pragma unroll
        for (int i = 1; i < 16; i <<= 1) ls[r] += __shfl_xor(ls[r], i, 64);
    }

    #pragma unroll
    for (int r = 0; r < 4; r++) {
        int row = quad * 4 + r;
        if (l16 == 0) lbuf[wv][row] = ls[r];
        obuf[wv][row][l16] = o0[r];
        obuf[wv][row][16 + l16] = o1[r];
    }
    __syncthreads();

    // merge: plain sums (no exp/max needed)
    int row = threadIdx.x >> 4, col = threadIdx.x & 15;
    float L = 0.f, a0 = 0.f, a1 = 0.f;
    #pragma unroll
    for (int w = 0; w < 4; w++) {
        L  += lbuf[w][row];
        a0 += obuf[w][row][col];
        a1 += obuf[w][row][16 + col];
    }
    int l = lt * 16 + row;
    if (l < LQ) {
        float inv = 1.0f / L;
        size_t base = ((size_t)l * NB + n) * EE + h * DH;
        ows[base + col]      = f2bf(a0 * inv);
        ows[base + 16 + col] = f2bf(a1 * inv);
    }
}

// ---------------------------------------------------------------------------
// Output projection: wave = 16 tokens x 256 features, bf16 A/B, fp32 out
// ---------------------------------------------------------------------------
__global__ __launch_bounds__(256) void oproj_kernel(
    const short* __restrict__ xa, const short* __restrict__ wbf,
    const float* __restrict__ bias, float* __restrict__ out)
{
    int wave = (blockIdx.x * 256 + threadIdx.x) >> 6;
    int lid = threadIdx.x & 63, quad = lid >> 4, l16 = lid & 15;
    int t = wave * 16 + l16;

    const short* wb = wbf + 3 * EE * EE;
    f32x4 acc[16];
    #pragma unroll
    for (int f = 0; f < 16; f++) acc[f] = (f32x4){0.f, 0.f, 0.f, 0.f};

    for (int ks = 0; ks < 8; ks++) {
        short8 af = *(const short8*)(xa + (size_t)t * EE + ks * 32 + quad * 8);
        #pragma unroll
        for (int f = 0; f < 16; f++) {
            short8 bf = *(const short8*)(wb + (size_t)(f * 16 + l16) * EE + ks * 32 + quad * 8);
            acc[f] = MFMA16(af, bf, acc[f]);
        }
    }

    #pragma unroll
    for (int f = 0; f < 16; f++) {
        int e = f * 16 + l16;
        float bi = bias[e];
        #pragma unroll
        for (int r = 0; r < 4; r++) {
            int tok = wave * 16 + quad * 4 + r;
            out[(size_t)tok * EE + e] = acc[f][r] + bi;
        }
    }
}

extern "C" void kernel_launch(void* const* d_in, const int* in_sizes, int n_in,
                              void* d_out, int out_size, void* d_ws, size_t ws_size,
                              hipStream_t stream) {
    const float* query = (const float*)d_in[0];
    const float* key   = (const float*)d_in[1];
    const float* value = (const float*)d_in[2];
    const float* gauss = (const float*)d_in[3];
    const unsigned char* mask = (const unsigned char*)d_in[4];
    const float* ipw = (const float*)d_in[5];
    const float* ipb = (const float*)d_in[6];
    const float* opw = (const float*)d_in[7];
    const float* opb = (const float*)d_in[8];
    float* out = (float*)d_out;

    short* wbf = (short*)d_ws;                        // 262144 shorts
    short* qws = wbf + 4 * EE * EE;                   // 256*304*32
    short* kws = qws + (size_t)BH * LPAD * DH;        // 256*1024*32
    short* vws = kws + (size_t)BH * SK * DH;          // 256*1024*32
    short* vt  = vws + (size_t)BH * SK * DH;          // 256*32*1024
    short* ows = vt  + (size_t)BH * SK * DH;          // 9600*256

    prep_kernel<<<256, 256, 0, stream>>>(ipw, opw, wbf);
    proj_kernel<<<1174, 256, 0, stream>>>(query, key, value, wbf, ipb, qws, kws, vws);
    vtrans_kernel<<<1024, 256, 0, stream>>>(vws, vt);
    attn_kernel<<<BH * NLT, 256, 0, stream>>>(qws, kws, vt, gauss, mask, ows);
    oproj_kernel<<<150, 256, 0, stream>>>(ows, wbf, opb, out);
}